// Round 1
// baseline (460.486 us; speedup 1.0000x reference)
//
#include <hip/hip_runtime.h>

#define T_LEN 65536
#define C_CH 8
#define H_DIM 64
#define NCHUNK 256            // chunks per channel
#define CLEN (T_LEN / NCHUNK) // 256

__device__ __forceinline__ float bcast_lane(float v, int k) {
    return __uint_as_float(__builtin_amdgcn_readlane(__float_as_uint(v), k));
}

__global__ __launch_bounds__(64, 2) void gru_kernel(
    const float* __restrict__ x,     // (T,10,8)
    const int*   __restrict__ cg,    // (T,8)
    const int*   __restrict__ cs,    // (T,8)
    const float* __restrict__ W_ih,  // (8,192,4)
    const float* __restrict__ W_hh,  // (8,192,64)
    const float* __restrict__ b_ih,  // (8,192)
    const float* __restrict__ b_hh,  // (8,192)
    const float* __restrict__ W_out, // (8,1,64)
    const float* __restrict__ b_out, // (8,)
    float* __restrict__ y)           // (T,)
{
    const int lane = threadIdx.x;
    const int c    = blockIdx.x & 7;
    const int j    = blockIdx.x >> 3;

    // Chunk boundaries aligned to contour starts: S = first start >= j*CLEN.
    // cs[0][c]==1 is guaranteed, so chunk 0 starts at 0 and chunks tile [0,T).
    auto find_start = [&](int from) -> int {
        for (int b = from; b < T_LEN; b += 64) {
            int t = b + lane;
            int f = 0;
            if (t < T_LEN) f = cs[t * C_CH + c];
            unsigned long long m = __ballot(f == 1);
            if (m) return b + (int)(__ffsll((long long)m) - 1);
        }
        return T_LEN;
    };
    const int S = find_start(j * CLEN);
    const int E = (j == NCHUNK - 1) ? T_LEN : find_start((j + 1) * CLEN);

    // Lane i holds W_hh rows {i, i+64, i+128} of channel c: 192 VGPRs.
    float wr[H_DIM], wz[H_DIM], wn[H_DIM];
    const float* Wc = W_hh + c * 192 * 64;
#pragma unroll
    for (int q = 0; q < 16; ++q) {
        float4 a = *(const float4*)(Wc + (lane      ) * 64 + q * 4);
        float4 b = *(const float4*)(Wc + (lane +  64) * 64 + q * 4);
        float4 d = *(const float4*)(Wc + (lane + 128) * 64 + q * 4);
        wr[4*q+0] = a.x; wr[4*q+1] = a.y; wr[4*q+2] = a.z; wr[4*q+3] = a.w;
        wz[4*q+0] = b.x; wz[4*q+1] = b.y; wz[4*q+2] = b.z; wz[4*q+3] = b.w;
        wn[4*q+0] = d.x; wn[4*q+1] = d.y; wn[4*q+2] = d.z; wn[4*q+3] = d.w;
    }

    const float* Wic = W_ih + c * 192 * 4;
    const float4 wir = *(const float4*)(Wic + (lane      ) * 4);
    const float4 wiz = *(const float4*)(Wic + (lane +  64) * 4);
    const float4 win = *(const float4*)(Wic + (lane + 128) * 4);
    const float bir = b_ih[c * 192 + lane];
    const float biz = b_ih[c * 192 + lane + 64];
    const float bin_ = b_ih[c * 192 + lane + 128];
    const float bhr = b_hh[c * 192 + lane];
    const float bhz = b_hh[c * 192 + lane + 64];
    const float bhn = b_hh[c * 192 + lane + 128];
    const float wo  = W_out[c * 64 + lane];
    const float bo  = b_out[c];

    float h = 0.0f;
    for (int t = S; t < E; ++t) {
        // wave-uniform per-step data (scalar loads, hidden under the FMA body)
        const int startf = cs[t * C_CH + c];
        const int active = cg[t * C_CH + c];
        const float x1 = x[t * 80 +  8 + c];
        const float x2 = x[t * 80 + 16 + c];
        const float x3 = x[t * 80 + 24 + c];
        const float x4v = x[t * 80 + 32 + c];

        if (startf) h = 0.0f;

        // gh = W_hh @ h + b_hh   (h broadcast lane-by-lane via v_readlane)
        float aR = bhr, aZ = bhz, aN = bhn;
#pragma unroll
        for (int k = 0; k < H_DIM; ++k) {
            const float hk = bcast_lane(h, k);
            aR = fmaf(wr[k], hk, aR);
            aZ = fmaf(wz[k], hk, aZ);
            aN = fmaf(wn[k], hk, aN);
        }

        // gx = W_ih @ x4 + b_ih (per-lane rows)
        float gxr = fmaf(wir.x, x1, fmaf(wir.y, x2, fmaf(wir.z, x3, fmaf(wir.w, x4v, bir))));
        float gxz = fmaf(wiz.x, x1, fmaf(wiz.y, x2, fmaf(wiz.z, x3, fmaf(wiz.w, x4v, biz))));
        float gxn = fmaf(win.x, x1, fmaf(win.y, x2, fmaf(win.z, x3, fmaf(win.w, x4v, bin_))));

        const float ar = gxr + aR;
        const float az = gxz + aZ;
        const float r  = 1.0f / (1.0f + __expf(-ar));
        const float z  = 1.0f / (1.0f + __expf(-az));
        float an = fmaf(r, aN, gxn);
        an = fmaxf(an, -40.0f);                 // avoid exp overflow -> NaN
        const float e2 = __expf(-2.0f * an);
        const float n  = (1.0f - e2) / (1.0f + e2);
        h = (1.0f - z) * n + z * h;

        // y[t] += active * (W_out . h + b_out)
        float p = wo * h;
#pragma unroll
        for (int o = 32; o; o >>= 1) p += __shfl_xor(p, o);
        if (lane == 0 && active) atomicAdd(y + t, p + bo);
    }
}

extern "C" void kernel_launch(void* const* d_in, const int* in_sizes, int n_in,
                              void* d_out, int out_size, void* d_ws, size_t ws_size,
                              hipStream_t stream) {
    const float* x     = (const float*)d_in[0];
    const int*   cg    = (const int*)  d_in[1];
    const int*   cs    = (const int*)  d_in[2];
    const float* W_ih  = (const float*)d_in[3];
    const float* W_hh  = (const float*)d_in[4];
    const float* b_ih  = (const float*)d_in[5];
    const float* b_hh  = (const float*)d_in[6];
    const float* W_out = (const float*)d_in[7];
    const float* b_out = (const float*)d_in[8];
    float* y = (float*)d_out;

    hipMemsetAsync(y, 0, (size_t)out_size * sizeof(float), stream);
    gru_kernel<<<NCHUNK * C_CH, 64, 0, stream>>>(x, cg, cs, W_ih, W_hh, b_ih, b_hh,
                                                 W_out, b_out, y);
}

// Round 2
// 245.397 us; speedup vs baseline: 1.8765x; 1.8765x over previous
//
#include <hip/hip_runtime.h>

#define T_LEN 65536
#define C_CH 8
#define NCHUNK 256            // chunks per channel
#define CLEN (T_LEN / NCHUNK) // 256

typedef float v2f __attribute__((ext_vector_type(2)));

__device__ __forceinline__ float bcast(float v, int k) {
    return __uint_as_float(__builtin_amdgcn_readlane(__float_as_uint(v), k));
}

__global__ __launch_bounds__(64, 2) void gru_kernel(
    const float* __restrict__ x,     // (T,10,8)
    const int*   __restrict__ cg,    // (T,8)
    const int*   __restrict__ cs,    // (T,8)
    const float* __restrict__ W_ih,  // (8,192,4)
    const float* __restrict__ W_hh,  // (8,192,64)
    const float* __restrict__ b_ih,  // (8,192)
    const float* __restrict__ b_hh,  // (8,192)
    const float* __restrict__ W_out, // (8,1,64)
    const float* __restrict__ b_out, // (8,)
    float* __restrict__ y)           // (T,)
{
    __shared__ float p_lds[64 * 65];   // [step][lane], stride 65 = conflict-free transpose
    const int lane = threadIdx.x;
    // all 8 channels of the same time-range land on the same XCD (bid%8 == j%8)
    const int c    = blockIdx.x >> 8;
    const int j    = blockIdx.x & 255;

    // Chunk boundaries aligned to contour starts: S = first start >= j*CLEN.
    // cs[0][c]==1 guaranteed, so chunks tile [0,T) and every chunk begins at h=0.
    auto find_start = [&](int from) -> int {
        for (int b = from; b < T_LEN; b += 64) {
            int t = b + lane;
            int f = 0;
            if (t < T_LEN) f = cs[t * C_CH + c];
            unsigned long long m = __ballot(f == 1);
            if (m) return b + (int)(__ffsll((long long)m) - 1);
        }
        return T_LEN;
    };
    const int S = find_start(j * CLEN);
    const int E = (j == NCHUNK - 1) ? T_LEN : find_start((j + 1) * CLEN);

    // Lane i holds W_hh rows {i, i+64, i+128} of channel c, packed as float2 pairs
    // (96 v2f = 192 VGPRs; packed so ISel can form v_pk_fma_f32).
    v2f wr2[32], wz2[32], wn2[32];
    const float* Wc = W_hh + c * 192 * 64;
#pragma unroll
    for (int q = 0; q < 16; ++q) {
        float4 a = *(const float4*)(Wc + (lane      ) * 64 + q * 4);
        float4 b = *(const float4*)(Wc + (lane +  64) * 64 + q * 4);
        float4 d = *(const float4*)(Wc + (lane + 128) * 64 + q * 4);
        wr2[2*q] = (v2f){a.x, a.y}; wr2[2*q+1] = (v2f){a.z, a.w};
        wz2[2*q] = (v2f){b.x, b.y}; wz2[2*q+1] = (v2f){b.z, b.w};
        wn2[2*q] = (v2f){d.x, d.y}; wn2[2*q+1] = (v2f){d.z, d.w};
    }

    const float* Wic = W_ih + c * 192 * 4;
    const float4 wir = *(const float4*)(Wic + (lane      ) * 4);
    const float4 wiz = *(const float4*)(Wic + (lane +  64) * 4);
    const float4 win = *(const float4*)(Wic + (lane + 128) * 4);
    const float bir  = b_ih[c * 192 + lane];
    const float biz  = b_ih[c * 192 + lane + 64];
    const float bin_ = b_ih[c * 192 + lane + 128];
    const float bhr  = b_hh[c * 192 + lane];
    const float bhz  = b_hh[c * 192 + lane + 64];
    const float bhn  = b_hh[c * 192 + lane + 128];
    const float wo   = W_out[c * 64 + lane];
    const float bo   = b_out[c];

    float h = 0.0f;
    for (int base = S; base < E; base += 64) {
        // ---- per-64-step prefetch: lane L owns step base+L ----
        const int t = base + lane;
        float4 xv = make_float4(0.f, 0.f, 0.f, 0.f);
        int csv = 0, cgv = 0;
        if (t < E) {
            const float* xp = x + (size_t)t * 80 + 8 + c;
            xv.x = xp[0]; xv.y = xp[8]; xv.z = xp[16]; xv.w = xp[24];
            csv = cs[t * C_CH + c];
            cgv = cg[t * C_CH + c];
        }
        const unsigned long long mstart = __ballot(csv == 1);
        const unsigned long long mact   = __ballot(cgv == 1);
        const int ns = min(64, E - base);

        for (int s = 0; s < ns; ++s) {
            if ((mstart >> s) & 1ull) h = 0.0f;   // wave-uniform

            // gh = W_hh @ h + b_hh, packed-fp32 (3 gates x 32 pk-FMA)
            v2f aR = (v2f){bhr, 0.f}, aZ = (v2f){bhz, 0.f}, aN = (v2f){bhn, 0.f};
#pragma unroll
            for (int m = 0; m < 32; ++m) {
                v2f h2;
                h2.x = bcast(h, 2 * m);
                h2.y = bcast(h, 2 * m + 1);
                aR = __builtin_elementwise_fma(wr2[m], h2, aR);
                aZ = __builtin_elementwise_fma(wz2[m], h2, aZ);
                aN = __builtin_elementwise_fma(wn2[m], h2, aN);
            }

            // gx from register-prefetched x, broadcast from owning lane
            const float x1 = bcast(xv.x, s), x2 = bcast(xv.y, s);
            const float x3 = bcast(xv.z, s), x4v = bcast(xv.w, s);
            float gxr = fmaf(wir.x, x1, fmaf(wir.y, x2, fmaf(wir.z, x3, fmaf(wir.w, x4v, bir))));
            float gxz = fmaf(wiz.x, x1, fmaf(wiz.y, x2, fmaf(wiz.z, x3, fmaf(wiz.w, x4v, biz))));
            float gxn = fmaf(win.x, x1, fmaf(win.y, x2, fmaf(win.z, x3, fmaf(win.w, x4v, bin_))));

            const float ar = gxr + aR.x + aR.y;
            const float az = gxz + aZ.x + aZ.y;
            const float r  = 1.0f / (1.0f + __expf(-ar));
            const float z  = 1.0f / (1.0f + __expf(-az));
            float an = fmaf(r, aN.x + aN.y, gxn);
            an = fmaxf(an, -40.0f);               // avoid exp overflow -> NaN
            const float e2 = __expf(-2.0f * an);
            const float n  = (1.0f - e2) / (1.0f + e2);
            h = (1.0f - z) * n + z * h;

            p_lds[s * 65 + lane] = wo * h;        // one ds_write, no wait
        }
        __syncthreads();

        // transpose-reduce: lane L sums step L's 64 partials, one coalesced atomic
        float sum = 0.f;
        for (int k = 0; k < 64; ++k) sum += p_lds[lane * 65 + k];
        if (lane < ns && ((mact >> lane) & 1ull))
            atomicAdd(y + base + lane, sum + bo);
        __syncthreads();
    }
}

extern "C" void kernel_launch(void* const* d_in, const int* in_sizes, int n_in,
                              void* d_out, int out_size, void* d_ws, size_t ws_size,
                              hipStream_t stream) {
    const float* x     = (const float*)d_in[0];
    const int*   cg    = (const int*)  d_in[1];
    const int*   cs    = (const int*)  d_in[2];
    const float* W_ih  = (const float*)d_in[3];
    const float* W_hh  = (const float*)d_in[4];
    const float* b_ih  = (const float*)d_in[5];
    const float* b_hh  = (const float*)d_in[6];
    const float* W_out = (const float*)d_in[7];
    const float* b_out = (const float*)d_in[8];
    float* y = (float*)d_out;

    hipMemsetAsync(y, 0, (size_t)out_size * sizeof(float), stream);
    gru_kernel<<<NCHUNK * C_CH, 64, 0, stream>>>(x, cg, cs, W_ih, W_hh, b_ih, b_hh,
                                                 W_out, b_out, y);
}

// Round 3
// 120.627 us; speedup vs baseline: 3.8174x; 2.0343x over previous
//
#include <hip/hip_runtime.h>

#define T_LEN 65536
#define C_CH 8
#define CLEN 32
#define NB 16
#define WIN (CLEN * NB)              // 512 nominal steps per wave-window
#define NBLK ((T_LEN / WIN) * C_CH)  // 128 windows/ch * 8 ch = 1024 blocks
#define SCANW 11                     // 704 bits scanned per window
#define MAXB 64                      // step-block size (mask word width)

typedef short bf16x8 __attribute__((ext_vector_type(8)));
typedef float f32x4 __attribute__((ext_vector_type(4)));
typedef unsigned int uint;
typedef unsigned long long u64;

#define MFMA32 __builtin_amdgcn_mfma_f32_16x16x32_bf16

__device__ __forceinline__ uint f2bf(float f) {           // RNE float->bf16
    uint u = __float_as_uint(f);
    return (u + 0x7FFFu + ((u >> 16) & 1u)) >> 16;
}
__device__ __forceinline__ uint pk(float a, float b) {
    return f2bf(a) | (f2bf(b) << 16);
}
__device__ __forceinline__ bf16x8 mk8(uint a, uint b, uint c, uint d) {
    union { uint u[4]; bf16x8 v; } x;
    x.u[0] = a; x.u[1] = b; x.u[2] = c; x.u[3] = d;
    return x.v;
}

__global__ __launch_bounds__(64, 1) void gru_mfma(
    const float* __restrict__ x,     // (T,10,8)
    const int*   __restrict__ cg,    // (T,8)
    const int*   __restrict__ cs,    // (T,8)
    const float* __restrict__ W_ih,  // (8,192,4)
    const float* __restrict__ W_hh,  // (8,192,64)
    const float* __restrict__ b_ih,  // (8,192)
    const float* __restrict__ b_hh,  // (8,192)
    const float* __restrict__ W_out, // (8,1,64)
    const float* __restrict__ b_out, // (8,)
    float* __restrict__ y)           // (T,)
{
    __shared__ u64 stw[SCANW], acw[SCANW];
    __shared__ int sb[NB + 1];
    __shared__ float yw[NB][MAXB + 4];
    __shared__ uint2 bxl[MAXB][NB];

    const int lane = threadIdx.x;
    const int l15 = lane & 15, l4 = lane >> 4;
    // decode: all 8 channels of one time-window share an XCD (bid%8 = window%8)
    const int slot = blockIdx.x & 7, rest = blockIdx.x >> 3;
    const int c = rest & 7, whi = rest >> 3;
    const int w = whi * 8 + slot;            // window id 0..127
    const int RB = w * WIN;

    // ---- cooperative scan of cs/cg bits over [RB, RB+704) ----
    for (int rr = 0; rr < SCANW; ++rr) {
        int t = RB + rr * 64 + lane;
        int sv = 0, av = 0;
        if (t < T_LEN) { sv = cs[t * C_CH + c]; av = cg[t * C_CH + c]; }
        u64 m1 = __ballot(sv == 1);
        u64 m2 = __ballot(av == 1);
        if (lane == 0) { stw[rr] = m1; acw[rr] = m2; }
    }
    __syncthreads();

    // ---- 17 start-aligned boundaries: sb[k] = first start >= RB + k*CLEN ----
    if (lane <= NB) {
        int rel = lane * CLEN;
        int q = rel >> 6, r0 = rel & 63;
        u64 m = stw[q] >> r0;
        int pos = -1;
        if (m) pos = rel + __ffsll(m) - 1;
        else {
            for (int q2 = q + 1; q2 < SCANW; ++q2)
                if (stw[q2]) { pos = (q2 << 6) + __ffsll(stw[q2]) - 1; break; }
        }
        int Sa;
        if (pos >= 0) Sa = RB + pos;
        else {  // ultra-rare fallback: continue serial scan past region
            int t = RB + SCANW * 64;
            while (t < T_LEN && cs[t * C_CH + c] != 1) ++t;
            Sa = t;
        }
        sb[lane] = min(Sa, T_LEN);
    }
    __syncthreads();

    const int S = sb[l15];              // this lane's column's chunk start
    const int len = sb[l15 + 1] - S;    // its length (may be 0)
    int Lmax = len;
#pragma unroll
    for (int o = 1; o < 16; o <<= 1) Lmax = max(Lmax, __shfl_xor(Lmax, o));

    // ---- A-fragments (constants for the whole window) ----
    // W_hh as 12 M-tiles x 2 K-tiles, lane holds A[l15][4*l4+i (+16 half)]
    const float* Wc = W_hh + c * 192 * 64;
    uint Ah[12][2][4];
#pragma unroll
    for (int tm = 0; tm < 12; ++tm)
#pragma unroll
        for (int kt = 0; kt < 2; ++kt) {
            const float* p = Wc + (16 * tm + l15) * 64 + 32 * kt + 4 * l4;
            float4 a = *(const float4*)p;
            float4 b = *(const float4*)(p + 16);
            Ah[tm][kt][0] = pk(a.x, a.y);
            Ah[tm][kt][1] = pk(a.z, a.w);
            Ah[tm][kt][2] = pk(b.x, b.y);
            Ah[tm][kt][3] = pk(b.z, b.w);
        }
    // W_ih + bias tiles (K=32 frag, only k=0..4 nonzero -> store 2 dwords)
    // k=0..3: W_ih cols; k=4 ("ones" column of Bx): bias.
    // r/z tiles (0..7): bias = b_ih+b_hh (merged pre-activation);
    // n tiles (8..11): bias = b_ih only (gx_n accumulator).
    uint Axd[12][2];
#pragma unroll
    for (int tm = 0; tm < 12; ++tm) {
        int row = 16 * tm + l15;
        uint d0 = 0, d1 = 0;
        if (l4 == 0) {
            float4 wi = *(const float4*)(W_ih + (c * 192 + row) * 4);
            d0 = pk(wi.x, wi.y);
            d1 = pk(wi.z, wi.w);
        } else if (l4 == 1) {
            float bias = (tm < 8) ? (b_ih[c * 192 + row] + b_hh[c * 192 + row])
                                  : b_ih[c * 192 + row];
            d0 = f2bf(bias);
        }
        Axd[tm][0] = d0; Axd[tm][1] = d1;
    }
    uint Abn[4];  // n-gate gh bias (b_hh), rides the same ones-column
#pragma unroll
    for (int tn = 0; tn < 4; ++tn)
        Abn[tn] = (l4 == 1) ? f2bf(b_hh[c * 192 + 128 + 16 * tn + l15]) : 0u;

    float wof[16];
#pragma unroll
    for (int tm = 0; tm < 4; ++tm) {
        float4 v = *(const float4*)(W_out + c * 64 + 16 * tm + 4 * l4);
        wof[4 * tm + 0] = v.x; wof[4 * tm + 1] = v.y;
        wof[4 * tm + 2] = v.z; wof[4 * tm + 3] = v.w;
    }
    const float bo = b_out[c];

    // ---- state: h fp32 (D-layout) + bf16 B-frags (same lane mapping) ----
    float h[16];
    uint B0[4], B1[4];
#pragma unroll
    for (int i = 0; i < 16; ++i) h[i] = 0.f;
#pragma unroll
    for (int i = 0; i < 4; ++i) { B0[i] = 0u; B1[i] = 0u; }
    const uint bx_c0 = (l4 == 1) ? 0x00003F80u : 0u;  // bf16(1.0) at k=4

    for (int s0 = 0; s0 < Lmax; s0 += MAXB) {
        const int Lb = min(MAXB, Lmax - s0);

        // stage Bx payloads: bxl[s][b] = packed bf16 {x1,x2,x3,x4}(t = S_b+s0+s)
        const int npair = Lb * NB;
        for (int p = lane; p < npair; p += 64) {
            int b = p & 15, s = p >> 4;
            int t = min(sb[b] + s0 + s, T_LEN - 1);
            const float* xp = x + (size_t)t * 80 + 8 + c;
            bxl[s][b] = make_uint2(pk(xp[0], xp[8]), pk(xp[16], xp[24]));
        }
        // per-lane 64-bit reset mask for its column, this step-block
        int off = (S - RB) + s0;
        int q = off >> 6, r0 = off & 63;
        u64 w0s = stw[q], w1s = (q + 1 < SCANW) ? stw[q + 1] : 0ull;
        u64 ms = (w0s >> r0) | (r0 ? (w1s << (64 - r0)) : 0ull);
        __syncthreads();

        for (int s = 0; s < Lb; ++s) {
            const bool rst = (ms >> s) & 1;
#pragma unroll
            for (int i = 0; i < 16; ++i) h[i] = rst ? 0.f : h[i];
#pragma unroll
            for (int i = 0; i < 4; ++i) {
                B0[i] = rst ? 0u : B0[i];
                B1[i] = rst ? 0u : B1[i];
            }

            uint2 bx = bxl[s][l15];
            const bf16x8 Bx  = mk8((lane < 16) ? bx.x : bx_c0,
                                   (lane < 16) ? bx.y : 0u, 0u, 0u);
            const bf16x8 Bh0 = mk8(B0[0], B0[1], B0[2], B0[3]);
            const bf16x8 Bh1 = mk8(B1[0], B1[1], B1[2], B1[3]);
            const f32x4 z4 = {0.f, 0.f, 0.f, 0.f};

            f32x4 accR[4], accZ[4], accN[4], agx[4];
#pragma unroll
            for (int tm = 0; tm < 4; ++tm) {
                f32x4 a = MFMA32(mk8(Axd[tm][0], Axd[tm][1], 0u, 0u), Bx, z4, 0, 0, 0);
                a = MFMA32(mk8(Ah[tm][0][0], Ah[tm][0][1], Ah[tm][0][2], Ah[tm][0][3]), Bh0, a, 0, 0, 0);
                a = MFMA32(mk8(Ah[tm][1][0], Ah[tm][1][1], Ah[tm][1][2], Ah[tm][1][3]), Bh1, a, 0, 0, 0);
                accR[tm] = a;
                int tz = tm + 4;
                f32x4 b = MFMA32(mk8(Axd[tz][0], Axd[tz][1], 0u, 0u), Bx, z4, 0, 0, 0);
                b = MFMA32(mk8(Ah[tz][0][0], Ah[tz][0][1], Ah[tz][0][2], Ah[tz][0][3]), Bh0, b, 0, 0, 0);
                b = MFMA32(mk8(Ah[tz][1][0], Ah[tz][1][1], Ah[tz][1][2], Ah[tz][1][3]), Bh1, b, 0, 0, 0);
                accZ[tm] = b;
                int tn = tm + 8;
                agx[tm] = MFMA32(mk8(Axd[tn][0], Axd[tn][1], 0u, 0u), Bx, z4, 0, 0, 0);
                f32x4 g = MFMA32(mk8(Abn[tm], 0u, 0u, 0u), Bx, z4, 0, 0, 0);
                g = MFMA32(mk8(Ah[tn][0][0], Ah[tn][0][1], Ah[tn][0][2], Ah[tn][0][3]), Bh0, g, 0, 0, 0);
                g = MFMA32(mk8(Ah[tn][1][0], Ah[tn][1][1], Ah[tn][1][2], Ah[tn][1][3]), Bh1, g, 0, 0, 0);
                accN[tm] = g;
            }

            float yp = 0.f;
            uint nB[8];
#pragma unroll
            for (int tm = 0; tm < 4; ++tm) {
                float hv[4];
#pragma unroll
                for (int i = 0; i < 4; ++i) {
                    float rr = 1.f / (1.f + __expf(-accR[tm][i]));
                    float zz = 1.f / (1.f + __expf(-accZ[tm][i]));
                    float np = fmaf(rr, accN[tm][i], agx[tm][i]);
                    np = fmaxf(np, -40.f);
                    float e2 = __expf(-2.f * np);
                    float nn = (1.f - e2) / (1.f + e2);
                    float hh = fmaf(zz, h[4 * tm + i] - nn, nn);
                    h[4 * tm + i] = hh;
                    hv[i] = hh;
                    yp = fmaf(wof[4 * tm + i], hh, yp);
                }
                nB[2 * tm]     = pk(hv[0], hv[1]);
                nB[2 * tm + 1] = pk(hv[2], hv[3]);
            }
            // D-layout == B-layout: tiles 0,1 -> Bh0 halves; 2,3 -> Bh1 halves
            B0[0] = nB[0]; B0[1] = nB[1]; B0[2] = nB[2]; B0[3] = nB[3];
            B1[0] = nB[4]; B1[1] = nB[5]; B1[2] = nB[6]; B1[3] = nB[7];

            float t1 = yp + __shfl_xor(yp, 16);
            float t2 = t1 + __shfl_xor(t1, 32);
            if (lane < 16 && (s0 + s) < len) yw[lane][s] = t2;
        }
        __syncthreads();

        // write back this block's outputs: one coalesced atomic row per chunk
        for (int b = 0; b < NB; ++b) {
            int Sb = sb[b];
            int lenb = sb[b + 1] - Sb;
            int sg = s0 + lane;
            if (lane < Lb && sg < lenb) {
                int offa = (Sb - RB) + sg;
                int qa = offa >> 6;
                u64 wa = (qa < SCANW) ? acw[qa] : 0ull;
                if ((wa >> (offa & 63)) & 1)
                    atomicAdd(&y[Sb + sg], yw[b][lane] + bo);
            }
        }
        __syncthreads();
    }
}

extern "C" void kernel_launch(void* const* d_in, const int* in_sizes, int n_in,
                              void* d_out, int out_size, void* d_ws, size_t ws_size,
                              hipStream_t stream) {
    const float* x     = (const float*)d_in[0];
    const int*   cg    = (const int*)  d_in[1];
    const int*   cs    = (const int*)  d_in[2];
    const float* W_ih  = (const float*)d_in[3];
    const float* W_hh  = (const float*)d_in[4];
    const float* b_ih  = (const float*)d_in[5];
    const float* b_hh  = (const float*)d_in[6];
    const float* W_out = (const float*)d_in[7];
    const float* b_out = (const float*)d_in[8];
    float* y = (float*)d_out;

    hipMemsetAsync(y, 0, (size_t)out_size * sizeof(float), stream);
    gru_mfma<<<NBLK, 64, 0, stream>>>(x, cg, cs, W_ih, W_hh, b_ih, b_hh,
                                      W_out, b_out, y);
}